// Round 13
// baseline (589.016 us; speedup 1.0000x reference)
//
#include <hip/hip_runtime.h>
#include <hip/hip_bf16.h>

#define NN 768
#define CSD 384
#define CZD 128
#define HD 12
#define DOUT 2112
#define II 3

#define SCALE_SINGLE 0.25f
#define SCALE_FRAME (-0.11785113019775793f)   /* -1/sqrt(72) */

__device__ __forceinline__ float dot4f(float4 a, float4 b){
    return fmaf(a.x,b.x, fmaf(a.y,b.y, fmaf(a.z,b.z, a.w*b.w)));
}

// ---------------- K1: projections + frame apply, II=3 residues per block ----------------
__global__ __launch_bounds__(384) void k_proj(
    const float* __restrict__ s, const float* __restrict__ R, const float* __restrict__ tv,
    const float* __restrict__ Wq, const float* __restrict__ Wk, const float* __restrict__ Wv,
    const float* __restrict__ Wqp, const float* __restrict__ Wkp, const float* __restrict__ Wvp,
    float* __restrict__ q, float* __restrict__ k, float* __restrict__ v,
    float* __restrict__ gq, float* __restrict__ gk, float* __restrict__ gv,
    float* __restrict__ sqq, float* __restrict__ sqk)
{
    __shared__ float s_l[II*CSD];
    __shared__ float praw[II][576];
    __shared__ float sq_pt[II][96];
    int i0 = blockIdx.x * II, t = threadIdx.x;
    if (t < II*CSD/4){
        const float4* s4 = (const float4*)(s + (size_t)i0*CSD);
        ((float4*)s_l)[t] = s4[t];
    }
    __syncthreads();

    int cols[3] = {t, t+384, t+768};
    const float* Wp[3]; int st[3], lc[3];
    #pragma unroll
    for (int m=0;m<3;m++){
        int c = cols[m];
        if (c < 192){ Wp[m]=Wq;  st[m]=192; lc[m]=c; }
        else if (c < 384){ Wp[m]=Wk;  st[m]=192; lc[m]=c-192; }
        else if (c < 576){ Wp[m]=Wv;  st[m]=192; lc[m]=c-384; }
        else if (c < 720){ Wp[m]=Wqp; st[m]=144; lc[m]=c-576; }
        else if (c < 864){ Wp[m]=Wkp; st[m]=144; lc[m]=c-720; }
        else { Wp[m]=Wvp; st[m]=288; lc[m]=c-864; }
    }
    float acc[3][II];
    #pragma unroll
    for (int m=0;m<3;m++)
        #pragma unroll
        for (int ii=0;ii<II;ii++) acc[m][ii]=0.f;

    #pragma unroll 4
    for (int r=0;r<CSD;r++){
        float w0 = Wp[0][(size_t)r*st[0]+lc[0]];
        float w1 = Wp[1][(size_t)r*st[1]+lc[1]];
        float w2 = Wp[2][(size_t)r*st[2]+lc[2]];
        #pragma unroll
        for (int ii=0;ii<II;ii++){
            float sv = s_l[ii*CSD + r];
            acc[0][ii] = fmaf(sv, w0, acc[0][ii]);
            acc[1][ii] = fmaf(sv, w1, acc[1][ii]);
            acc[2][ii] = fmaf(sv, w2, acc[2][ii]);
        }
    }
    #pragma unroll
    for (int m=0;m<3;m++){
        int c = cols[m];
        #pragma unroll
        for (int ii=0;ii<II;ii++){
            float val = acc[m][ii];
            size_t i = i0 + ii;
            if (c < 192) q[i*192 + c] = val;
            else if (c < 384) k[i*192 + (c-192)] = val;
            else if (c < 576) v[i*192 + (c-384)] = val;
            else praw[ii][c-576] = val;
        }
    }
    __syncthreads();

    if (t < 192){
        #pragma unroll
        for (int ii=0;ii<II;ii++){
            size_t i = i0 + ii;
            const float* Ri = R + i*9;
            float R00=Ri[0],R01=Ri[1],R02=Ri[2];
            float R10=Ri[3],R11=Ri[4],R12=Ri[5];
            float R20=Ri[6],R21=Ri[7],R22=Ri[8];
            float t0=tv[i*3+0],t1=tv[i*3+1],t2=tv[i*3+2];
            int src; float* dst; int sqslot=-1;
            if (t < 48){ src = t*3; dst = gq + i*144 + t*3; sqslot = t; }
            else if (t < 96){ int u=t-48; src = 144+u*3; dst = gk + i*144 + u*3; sqslot = 48+u; }
            else { int u=t-96; src = 288+u*3; dst = gv + i*288 + u*3; }
            float x=praw[ii][src], y=praw[ii][src+1], zc=praw[ii][src+2];
            float g0 = fmaf(R00,x, fmaf(R01,y, fmaf(R02,zc, t0)));
            float g1 = fmaf(R10,x, fmaf(R11,y, fmaf(R12,zc, t1)));
            float g2 = fmaf(R20,x, fmaf(R21,y, fmaf(R22,zc, t2)));
            dst[0]=g0; dst[1]=g1; dst[2]=g2;
            if (sqslot >= 0) sq_pt[ii][sqslot] = g0*g0 + g1*g1 + g2*g2;
        }
    }
    __syncthreads();
    if (t < II*HD){
        int ii = t / HD, h = t % HD;
        float s1 = sq_pt[ii][h*4]+sq_pt[ii][h*4+1]+sq_pt[ii][h*4+2]+sq_pt[ii][h*4+3];
        float s2 = sq_pt[ii][48+h*4]+sq_pt[ii][48+h*4+1]+sq_pt[ii][48+h*4+2]+sq_pt[ii][48+h*4+3];
        sqq[(size_t)(i0+ii)*HD + h] = s1;
        sqk[(size_t)(i0+ii)*HD + h] = s2;
    }
}

// ---------------- K2: fused IPA (R12 compute, counted-vmcnt pipeline) ----------------
// block = one i, 512 threads = 8 waves. LDS ~140KB, 1 block/CU.
// 3x 32KB tile buffers; staging by waves 0-3 only (their vmcnt counts staging loads
// exclusively); loop = WAITV(8) -> raw s_barrier -> STAGE(jt+2) -> compute.
// vmcnt never drains to 0 in the loop (2 tiles always in flight).
// No ds_writes inside pipelined loops -> raw barrier needs no lgkmcnt drain.
// Phase A: 12x 64-row swizzled tiles; waves 0-3 pair, 4-7 single/frame (their own
// global loads force compiler vmcnt waits, so they don't stage). Exchange+softmax
// unchanged. Phase B: 12x 64-row linear tiles; o_z (t<384), o_s/so (t in [384,504)).
__global__ __launch_bounds__(512) void k_ipa(
    const float* __restrict__ z, const float* __restrict__ Wb, const float* __restrict__ scale_head,
    const float* __restrict__ q, const float* __restrict__ k,
    const float* __restrict__ gq, const float* __restrict__ gk,
    const float* __restrict__ sqq, const float* __restrict__ sqk,
    const float* __restrict__ v, const float* __restrict__ gv,
    const float* __restrict__ R, const float* __restrict__ tv,
    float* __restrict__ att)
{
    __shared__ float ztile[3][64][CZD];   // 96KB: 3 staging buffers; reused as exchange
    __shared__ float wbT[HD*CZD];         // [h][c]
    __shared__ float qloc[360];           // q(192) gq(144) sqq(12) sp(12)
    __shared__ float a_l[HD][NN];         // softmax'd attention, block-local
    __shared__ float so_l[288];

    int i = blockIdx.x, t = threadIdx.x;
    int wave = t >> 6, lane = t & 63;
    bool stg = (t < 256);                 // waves 0-3 stage (pure-LDS compute roles)

    for (int idx=t; idx<HD*CZD; idx+=512){
        int h = idx >> 7, c = idx & 127;
        wbT[idx] = Wb[(size_t)c*HD + h];
    }
    if (t < 192) qloc[t] = q[(size_t)i*192 + t];
    else if (t < 336) qloc[t] = gq[(size_t)i*144 + (t-192)];
    else if (t < 348) qloc[t] = sqq[(size_t)i*HD + (t-336)];
    else if (t < 360){
        int h = t-348;
        float shv = scale_head[h];
        float sp = (shv > 20.f) ? shv : log1pf(__expf(shv));
        qloc[t] = SCALE_FRAME * sp;
    }

    const char* zi = (const char*)(z + (size_t)i*NN*CZD);
    float* zbase = &ztile[0][0][0];

#define WAITV(N) asm volatile("s_waitcnt vmcnt(" #N ")" ::: "memory")
#define BARX() do{ asm volatile("" ::: "memory"); __builtin_amdgcn_s_barrier(); asm volatile("" ::: "memory"); }while(0)

    // 64-row (32KB) tile staged by 256 threads x 8 x 16B. Phase A: swizzled source.
#define STAGEL(JT, BUF) do { \
    const char* _zb = zi + (size_t)(JT)*32768; \
    char* _lb = (char*)zbase + (size_t)(BUF)*32768; \
    _Pragma("unroll") \
    for (int _m=0;_m<8;_m++){ \
        int _d = t*16 + _m*4096; \
        int _j = _d >> 9; \
        int _b = _d & 511; \
        int _sb = _b ^ ((_j & 31) << 4); \
        __builtin_amdgcn_global_load_lds((const __attribute__((address_space(1))) void*)(_zb + (size_t)_j*512 + _sb), \
            (__attribute__((address_space(3))) void*)(_lb + _d), 16, 0, 0); \
    } \
  } while(0)

    // Phase B: linear both sides
#define STAGEB(JT, BUF) do { \
    const char* _zb = zi + (size_t)(JT)*32768; \
    char* _lb = (char*)zbase + (size_t)(BUF)*32768; \
    _Pragma("unroll") \
    for (int _m=0;_m<8;_m++){ \
        int _d = t*16 + _m*4096; \
        __builtin_amdgcn_global_load_lds((const __attribute__((address_space(1))) void*)(_zb + _d), \
            (__attribute__((address_space(3))) void*)(_lb + _d), 16, 0, 0); \
    } \
  } while(0)

    int hg = (wave < 4) ? wave : (wave - 4);
    int h0 = hg * 3;
    float L[12][3];

    __syncthreads();   // wbT/qloc published

    if (stg){ STAGEL(0, 0); STAGEL(1, 1); }

    {
        const float4* wb4 = (const float4*)wbT;
        const float4* qv4 = (const float4*)qloc;
        const float4* gq4 = (const float4*)(qloc + 192);
        int xoff = (lane & 31) << 4;

        for (int jt=0; jt<12; ++jt){
            if (stg){
                if (jt < 11) WAITV(8);   // tile jt landed; jt+1 still in flight
                else WAITV(0);
            }
            BARX();                      // all of tile jt visible; compute(jt-1) done everywhere
            if (stg && jt+2 < 12) STAGEL(jt+2, (jt+2)%3);
            int cur = jt % 3;
            if (wave < 4){
                const char* zb = (const char*)(zbase + (size_t)cur*8192) + lane*512;
                float p0=0.f, p1=0.f, p2=0.f;
                #pragma unroll 8
                for (int c4=0; c4<32; ++c4){
                    float4 zv = *(const float4*)(zb + ((c4*16) ^ xoff));
                    p0 += dot4f(zv, wb4[(h0+0)*32 + c4]);
                    p1 += dot4f(zv, wb4[(h0+1)*32 + c4]);
                    p2 += dot4f(zv, wb4[(h0+2)*32 + c4]);
                }
                L[jt][0]=p0; L[jt][1]=p1; L[jt][2]=p2;
            } else {
                int jg = jt*64 + lane;
                const float4* kp  = (const float4*)(k  + (size_t)jg*192);
                const float4* gkp = (const float4*)(gk + (size_t)jg*144);
                #pragma unroll
                for (int hs=0; hs<3; ++hs){
                    int h = h0 + hs;
                    float sng = dot4f(qv4[h*4+0], kp[h*4+0]) + dot4f(qv4[h*4+1], kp[h*4+1])
                              + dot4f(qv4[h*4+2], kp[h*4+2]) + dot4f(qv4[h*4+3], kp[h*4+3]);
                    float fdot = dot4f(gq4[h*3+0], gkp[h*3+0]) + dot4f(gq4[h*3+1], gkp[h*3+1])
                               + dot4f(gq4[h*3+2], gkp[h*3+2]);
                    float d2 = qloc[336+h] + sqk[(size_t)jg*HD + h] - 2.0f*fdot;
                    L[jt][hs] = fmaf(SCALE_SINGLE, sng, qloc[348+h]*d2);
                }
            }
        }
    }
    __syncthreads();   // last tile consumed everywhere; ztile free for exchange

    // exchange: single/frame waves deposit; pair waves add + softmax -> a_l
    float* S_l = zbase;
    if (wave >= 4){
        int base = (hg*64 + lane) * 37;
        #pragma unroll
        for (int jt=0; jt<12; ++jt)
            #pragma unroll
            for (int hs=0; hs<3; ++hs)
                S_l[base + jt*3 + hs] = L[jt][hs];
    }
    __syncthreads();
    if (wave < 4){
        int base = (hg*64 + lane) * 37;
        #pragma unroll
        for (int jt=0; jt<12; ++jt)
            #pragma unroll
            for (int hs=0; hs<3; ++hs)
                L[jt][hs] += S_l[base + jt*3 + hs];

        #pragma unroll
        for (int hs=0; hs<3; ++hs){
            float m = -1e30f;
            #pragma unroll
            for (int jt=0; jt<12; ++jt) m = fmaxf(m, L[jt][hs]);
            #pragma unroll
            for (int off=32; off; off>>=1) m = fmaxf(m, __shfl_xor(m, off));
            float ssum = 0.f;
            #pragma unroll
            for (int jt=0; jt<12; ++jt){ float e = __expf(L[jt][hs]-m); L[jt][hs]=e; ssum += e; }
            #pragma unroll
            for (int off=32; off; off>>=1) ssum += __shfl_xor(ssum, off);
            float inv = 1.0f/ssum;
            #pragma unroll
            for (int jt=0; jt<12; ++jt){
                a_l[h0+hs][jt*64 + lane] = L[jt][hs]*inv;
            }
        }
    }
    __syncthreads();   // a_l complete; exchange region free for phase B

    // ---------------- phase B ----------------
    if (stg){ STAGEB(0, 0); STAGEB(1, 1); }

    int hs = 0;
    const float4* gsrc = nullptr;
    int gstride = 0;
    if (t < 384){ hs = t>>5; }
    else if (t < 432){ int u=t-384; hs = u>>2; gsrc = (const float4*)v  + hs*4 + (u&3); gstride = 48; }
    else if (t < 504){ int u=t-432; hs = u/6;  gsrc = (const float4*)gv + hs*6 + (u%6); gstride = 72; }
    float4 acc = {0.f,0.f,0.f,0.f};
    int c4 = t & 31;

    for (int jt=0; jt<12; ++jt){
        if (stg){
            if (jt < 11) WAITV(8);
            else WAITV(0);
        }
        BARX();
        if (stg && jt+2 < 12) STAGEB(jt+2, (jt+2)%3);
        int cur = jt % 3;
        if (t < 384){
            const float4* arow4 = (const float4*)&a_l[hs][0];
            float4 af[16];
            #pragma unroll
            for (int m=0;m<16;m++) af[m] = arow4[jt*16 + m];
            const float4* zt4 = (const float4*)(zbase + (size_t)cur*8192);
            #pragma unroll
            for (int jj=0;jj<64;jj++){
                float aw = ((const float*)af)[jj];
                float4 zv = zt4[jj*32 + c4];
                acc.x = fmaf(aw, zv.x, acc.x);
                acc.y = fmaf(aw, zv.y, acc.y);
                acc.z = fmaf(aw, zv.z, acc.z);
                acc.w = fmaf(aw, zv.w, acc.w);
            }
        } else if (t < 504){
            const float* arow = &a_l[hs][0];
            #pragma unroll
            for (int jj=0;jj<64;jj++){
                int j = jt*64 + jj;
                float aw = arow[j];
                float4 sv = gsrc[(size_t)j*gstride];
                acc.x = fmaf(aw, sv.x, acc.x);
                acc.y = fmaf(aw, sv.y, acc.y);
                acc.z = fmaf(aw, sv.z, acc.z);
                acc.w = fmaf(aw, sv.w, acc.w);
            }
        }
    }
    __syncthreads();   // last tile consumed

    if (t < 384){
        float4* dst = (float4*)(att + (size_t)i*DOUT + 192) + (hs*32 + c4);
        *dst = acc;
    } else if (t < 432){
        int u = t-384;
        float4* dst = (float4*)(att + (size_t)i*DOUT) + u;
        *dst = acc;
    } else if (t < 504){
        int u = t-432;
        ((float4*)so_l)[u] = acc;
    }
    __syncthreads();
    if (t < 96){
        int h = t >> 3, p = t & 7;
        float d0 = so_l[h*24+p*3+0] - tv[(size_t)i*3+0];
        float d1 = so_l[h*24+p*3+1] - tv[(size_t)i*3+1];
        float d2 = so_l[h*24+p*3+2] - tv[(size_t)i*3+2];
        const float* Ri = R + (size_t)i*9;
        float l0 = fmaf(Ri[0],d0, fmaf(Ri[3],d1, Ri[6]*d2));
        float l1 = fmaf(Ri[1],d0, fmaf(Ri[4],d1, Ri[7]*d2));
        float l2 = fmaf(Ri[2],d0, fmaf(Ri[5],d1, Ri[8]*d2));
        size_t base = (size_t)i*DOUT;
        att[base + 1728 + p*36 + h*3 + 0] = l0;
        att[base + 1728 + p*36 + h*3 + 1] = l1;
        att[base + 1728 + p*36 + h*3 + 2] = l2;
        att[base + 2016 + p*12 + h] = sqrtf(l0*l0 + l1*l1 + l2*l2);
    }
#undef STAGEL
#undef STAGEB
#undef WAITV
#undef BARX
}

// ---------------- K4: final projection att @ Wout + bout, 3 rows/block ----------------
#define ROWS4 3
__global__ __launch_bounds__(384) void k_final(
    const float* __restrict__ att, const float* __restrict__ Wout, const float* __restrict__ bout,
    float* __restrict__ out)
{
    __shared__ float att_l[ROWS4*DOUT];
    int ib = blockIdx.x * ROWS4, t = threadIdx.x;
    for (int idx=t; idx<ROWS4*DOUT; idx+=384){
        att_l[idx] = att[(size_t)ib*DOUT + idx];
    }
    __syncthreads();
    float a0[ROWS4], a1[ROWS4], a2[ROWS4], a3[ROWS4];
    #pragma unroll
    for (int r=0;r<ROWS4;r++){ a0[r]=0.f; a1[r]=0.f; a2[r]=0.f; a3[r]=0.f; }
    #pragma unroll 2
    for (int d=0; d<DOUT; d+=4){
        float w0 = Wout[(size_t)(d+0)*CSD + t];
        float w1 = Wout[(size_t)(d+1)*CSD + t];
        float w2 = Wout[(size_t)(d+2)*CSD + t];
        float w3 = Wout[(size_t)(d+3)*CSD + t];
        #pragma unroll
        for (int r=0;r<ROWS4;r++){
            const float* al = att_l + r*DOUT + d;
            a0[r] = fmaf(al[0], w0, a0[r]);
            a1[r] = fmaf(al[1], w1, a1[r]);
            a2[r] = fmaf(al[2], w2, a2[r]);
            a3[r] = fmaf(al[3], w3, a3[r]);
        }
    }
    float bb = bout[t];
    #pragma unroll
    for (int r=0;r<ROWS4;r++){
        out[(size_t)(ib+r)*CSD + t] = bb + ((a0[r]+a1[r])+(a2[r]+a3[r]));
    }
}

extern "C" void kernel_launch(void* const* d_in, const int* in_sizes, int n_in,
                              void* d_out, int out_size, void* d_ws, size_t ws_size,
                              hipStream_t stream)
{
    const float* s   = (const float*)d_in[0];
    const float* z   = (const float*)d_in[1];
    const float* R   = (const float*)d_in[2];
    const float* tv  = (const float*)d_in[3];
    const float* Wq  = (const float*)d_in[4];
    const float* Wk  = (const float*)d_in[5];
    const float* Wv  = (const float*)d_in[6];
    const float* Wqp = (const float*)d_in[7];
    const float* Wkp = (const float*)d_in[8];
    const float* Wvp = (const float*)d_in[9];
    const float* Wb  = (const float*)d_in[10];
    const float* Wout= (const float*)d_in[11];
    const float* bout= (const float*)d_in[12];
    const float* sh  = (const float*)d_in[13];

    float* ws  = (float*)d_ws;
    float* q_  = ws;                 // 768*192
    float* k_  = q_  + 147456;       // 768*192
    float* v_  = k_  + 147456;       // 768*192
    float* gq_ = v_  + 147456;       // 768*144
    float* gk_ = gq_ + 110592;       // 768*144
    float* gv_ = gk_ + 110592;       // 768*288
    float* sqq_= gv_ + 221184;       // 768*12
    float* sqk_= sqq_ + 9216;        // 768*12
    float* att_= sqk_ + 9216;        // 768*2112
    float* out = (float*)d_out;

    hipLaunchKernelGGL(k_proj,  dim3(NN/II), dim3(384), 0, stream,
                       s,R,tv,Wq,Wk,Wv,Wqp,Wkp,Wvp, q_,k_,v_,gq_,gk_,gv_,sqq_,sqk_);
    hipLaunchKernelGGL(k_ipa,   dim3(NN),    dim3(512), 0, stream,
                       z,Wb,sh,q_,k_,gq_,gk_,sqq_,sqk_, v_,gv_,R,tv, att_);
    hipLaunchKernelGGL(k_final, dim3(NN/ROWS4), dim3(384), 0, stream,
                       att_,Wout,bout, out);
}

// Round 14
// 456.122 us; speedup vs baseline: 1.2914x; 1.2914x over previous
//
#include <hip/hip_runtime.h>
#include <hip/hip_bf16.h>

#define NN 768
#define CSD 384
#define CZD 128
#define HD 12
#define DOUT 2112
#define II 2

#define SCALE_SINGLE 0.25f
#define SCALE_FRAME (-0.11785113019775793f)   /* -1/sqrt(72) */

__device__ __forceinline__ float dot4f(float4 a, float4 b){
    return fmaf(a.x,b.x, fmaf(a.y,b.y, fmaf(a.z,b.z, a.w*b.w)));
}

// ---------------- K1: projections + frame apply, II=2 residues per block ----------------
__global__ __launch_bounds__(384) void k_proj(
    const float* __restrict__ s, const float* __restrict__ R, const float* __restrict__ tv,
    const float* __restrict__ Wq, const float* __restrict__ Wk, const float* __restrict__ Wv,
    const float* __restrict__ Wqp, const float* __restrict__ Wkp, const float* __restrict__ Wvp,
    float* __restrict__ q, float* __restrict__ k, float* __restrict__ v,
    float* __restrict__ gq, float* __restrict__ gk, float* __restrict__ gv,
    float* __restrict__ sqq, float* __restrict__ sqk)
{
    __shared__ float s_l[II*CSD];
    __shared__ float praw[II][576];
    __shared__ float sq_pt[II][96];
    int i0 = blockIdx.x * II, t = threadIdx.x;
    if (t < II*CSD/4){
        const float4* s4 = (const float4*)(s + (size_t)i0*CSD);
        ((float4*)s_l)[t] = s4[t];
    }
    __syncthreads();

    int cols[3] = {t, t+384, t+768};
    const float* Wp[3]; int st[3], lc[3];
    #pragma unroll
    for (int m=0;m<3;m++){
        int c = cols[m];
        if (c < 192){ Wp[m]=Wq;  st[m]=192; lc[m]=c; }
        else if (c < 384){ Wp[m]=Wk;  st[m]=192; lc[m]=c-192; }
        else if (c < 576){ Wp[m]=Wv;  st[m]=192; lc[m]=c-384; }
        else if (c < 720){ Wp[m]=Wqp; st[m]=144; lc[m]=c-576; }
        else if (c < 864){ Wp[m]=Wkp; st[m]=144; lc[m]=c-720; }
        else { Wp[m]=Wvp; st[m]=288; lc[m]=c-864; }
    }
    float acc[3][II];
    #pragma unroll
    for (int m=0;m<3;m++)
        #pragma unroll
        for (int ii=0;ii<II;ii++) acc[m][ii]=0.f;

    #pragma unroll 4
    for (int r=0;r<CSD;r++){
        float w0 = Wp[0][(size_t)r*st[0]+lc[0]];
        float w1 = Wp[1][(size_t)r*st[1]+lc[1]];
        float w2 = Wp[2][(size_t)r*st[2]+lc[2]];
        #pragma unroll
        for (int ii=0;ii<II;ii++){
            float sv = s_l[ii*CSD + r];
            acc[0][ii] = fmaf(sv, w0, acc[0][ii]);
            acc[1][ii] = fmaf(sv, w1, acc[1][ii]);
            acc[2][ii] = fmaf(sv, w2, acc[2][ii]);
        }
    }
    #pragma unroll
    for (int m=0;m<3;m++){
        int c = cols[m];
        #pragma unroll
        for (int ii=0;ii<II;ii++){
            float val = acc[m][ii];
            size_t i = i0 + ii;
            if (c < 192) q[i*192 + c] = val;
            else if (c < 384) k[i*192 + (c-192)] = val;
            else if (c < 576) v[i*192 + (c-384)] = val;
            else praw[ii][c-576] = val;
        }
    }
    __syncthreads();

    if (t < 192){
        #pragma unroll
        for (int ii=0;ii<II;ii++){
            size_t i = i0 + ii;
            const float* Ri = R + i*9;
            float R00=Ri[0],R01=Ri[1],R02=Ri[2];
            float R10=Ri[3],R11=Ri[4],R12=Ri[5];
            float R20=Ri[6],R21=Ri[7],R22=Ri[8];
            float t0=tv[i*3+0],t1=tv[i*3+1],t2=tv[i*3+2];
            int src; float* dst; int sqslot=-1;
            if (t < 48){ src = t*3; dst = gq + i*144 + t*3; sqslot = t; }
            else if (t < 96){ int u=t-48; src = 144+u*3; dst = gk + i*144 + u*3; sqslot = 48+u; }
            else { int u=t-96; src = 288+u*3; dst = gv + i*288 + u*3; }
            float x=praw[ii][src], y=praw[ii][src+1], zc=praw[ii][src+2];
            float g0 = fmaf(R00,x, fmaf(R01,y, fmaf(R02,zc, t0)));
            float g1 = fmaf(R10,x, fmaf(R11,y, fmaf(R12,zc, t1)));
            float g2 = fmaf(R20,x, fmaf(R21,y, fmaf(R22,zc, t2)));
            dst[0]=g0; dst[1]=g1; dst[2]=g2;
            if (sqslot >= 0) sq_pt[ii][sqslot] = g0*g0 + g1*g1 + g2*g2;
        }
    }
    __syncthreads();
    if (t < II*HD){
        int ii = t / HD, h = t % HD;
        float s1 = sq_pt[ii][h*4]+sq_pt[ii][h*4+1]+sq_pt[ii][h*4+2]+sq_pt[ii][h*4+3];
        float s2 = sq_pt[ii][48+h*4]+sq_pt[ii][48+h*4+1]+sq_pt[ii][48+h*4+2]+sq_pt[ii][48+h*4+3];
        sqq[(size_t)(i0+ii)*HD + h] = s1;
        sqk[(size_t)(i0+ii)*HD + h] = s2;
    }
}

// ---------------- K2: fused IPA (R12 structure; phase-A pair term with Wb in VGPRs) ----------------
// block = one i, 512 threads = 8 waves, LDS ~108KB -> 1 block/CU.
// Phase A: 12x 64-row swizzled z tiles, __syncthreads dbuf (R12-proven).
//   Pair waves 0-3: lane=(q=lane>>4, jl=lane&15). Wb slice (3 heads x 8 c4, c4=4cc+q)
//   preloaded into 24 f4 VGPRs -> ZERO Wb LDS reads in the tile loop (was 96/tile).
//   Lane reads rows 4jl..4jl+3 at its c4 set (32 b128, same as before), 12 partials,
//   quarter-reduce via shfl_xor(16/32), keeps r=q -> lane owns j_tile jj=4*jl+q.
//   jj is a pure lane-permutation: exchange read + a_l writes index by jj; softmax's
//   full-wave reductions are permutation-invariant. SF waves 4-7 unchanged.
// Phase B: unchanged from R12.
__global__ __launch_bounds__(512, 2) void k_ipa(
    const float* __restrict__ z, const float* __restrict__ Wb, const float* __restrict__ scale_head,
    const float* __restrict__ q, const float* __restrict__ k,
    const float* __restrict__ gq, const float* __restrict__ gk,
    const float* __restrict__ sqq, const float* __restrict__ sqk,
    const float* __restrict__ v, const float* __restrict__ gv,
    const float* __restrict__ R, const float* __restrict__ tv,
    float* __restrict__ att)
{
    __shared__ float ztile[2][64][CZD];   // 64KB: phase-A dbuf; reused as exchange + phase-B dbuf
    __shared__ float wbT[HD*CZD];         // [h][c]
    __shared__ float qloc[360];           // q(192) gq(144) sqq(12) sp(12)
    __shared__ float a_l[HD][NN];         // softmax'd attention, block-local
    __shared__ float so_l[288];

    int i = blockIdx.x, t = threadIdx.x;
    int wave = t >> 6, lane = t & 63;

    for (int idx=t; idx<HD*CZD; idx+=512){
        int h = idx >> 7, c = idx & 127;
        wbT[idx] = Wb[(size_t)c*HD + h];
    }
    if (t < 192) qloc[t] = q[(size_t)i*192 + t];
    else if (t < 336) qloc[t] = gq[(size_t)i*144 + (t-192)];
    else if (t < 348) qloc[t] = sqq[(size_t)i*HD + (t-336)];
    else if (t < 360){
        int h = t-348;
        float shv = scale_head[h];
        float sp = (shv > 20.f) ? shv : log1pf(__expf(shv));
        qloc[t] = SCALE_FRAME * sp;
    }

    const char* zi = (const char*)(z + (size_t)i*NN*CZD);
    float* zbase = &ztile[0][0][0];

    // phase A: 64-row tile (32KB), linear LDS dest, inverse-swizzled global src; all 512 threads
#define STAGEL(JT, BUF) do { \
    const char* _zb = zi + (size_t)(JT)*32768; \
    char* _lb = (char*)zbase + (size_t)(BUF)*32768; \
    _Pragma("unroll") \
    for (int _m=0;_m<4;_m++){ \
        int _d = t*16 + _m*8192; \
        int _j = _d >> 9; \
        int _b = _d & 511; \
        int _sb = _b ^ ((_j & 31) << 4); \
        __builtin_amdgcn_global_load_lds((const __attribute__((address_space(1))) void*)(_zb + (size_t)_j*512 + _sb), \
            (__attribute__((address_space(3))) void*)(_lb + _d), 16, 0, 0); \
    } \
  } while(0)

    // phase B: 32-row tile (16KB), linear, all 512 threads (2 x 16B each)
#define STAGEB(JT, BUF) do { \
    const float* _s = (const float*)zi + (size_t)(JT)*4096 + t*4; \
    float* _d = zbase + (size_t)(BUF)*4096 + t*4; \
    __builtin_amdgcn_global_load_lds((const __attribute__((address_space(1))) void*)_s, \
        (__attribute__((address_space(3))) void*)_d, 16, 0, 0); \
    __builtin_amdgcn_global_load_lds((const __attribute__((address_space(1))) void*)(_s+2048), \
        (__attribute__((address_space(3))) void*)(_d+2048), 16, 0, 0); \
  } while(0)

    STAGEL(0, 0);

    int hg = (wave < 4) ? wave : (wave - 4);
    int h0 = hg * 3;
    float L[12][3];

    int qq = lane >> 4, jl = lane & 15;
    int jj = jl*4 + qq;                    // pair-wave tile-local j this lane owns

    __syncthreads();   // wbT/qloc visible; STAGEL(0) drained

    // pair waves: preload Wb slice into registers (3 heads x 8 c4, c4 = cc*4+qq)
    float4 wbr[3][8];
    if (wave < 4){
        const float4* wb4 = (const float4*)wbT;
        #pragma unroll
        for (int hs=0; hs<3; ++hs)
            #pragma unroll
            for (int cc=0; cc<8; ++cc)
                wbr[hs][cc] = wb4[(h0+hs)*32 + cc*4 + qq];
    }

    {
        const float4* qv4 = (const float4*)qloc;
        const float4* gq4 = (const float4*)(qloc + 192);

        for (int jt=0; jt<12; ++jt){
            int cur = jt & 1;
            if (jt+1 < 12) STAGEL(jt+1, cur^1);
            if (wave < 4){
                const char* zb = (const char*)(zbase + (size_t)cur*8192);
                float p[4][3];
                #pragma unroll
                for (int r=0;r<4;r++)
                    #pragma unroll
                    for (int hs=0;hs<3;hs++) p[r][hs]=0.f;
                #pragma unroll
                for (int r=0; r<4; ++r){
                    int row = jl*4 + r;
                    const char* zr = zb + (size_t)row*512;
                    int xo = (row & 31) << 4;
                    #pragma unroll
                    for (int cc=0; cc<8; ++cc){
                        float4 zv = *(const float4*)(zr + ((16*(cc*4+qq)) ^ xo));
                        p[r][0] += dot4f(zv, wbr[0][cc]);
                        p[r][1] += dot4f(zv, wbr[1][cc]);
                        p[r][2] += dot4f(zv, wbr[2][cc]);
                    }
                }
                // reduce partial sums over the 4 c-quarters (lanes differing in bits 4,5)
                #pragma unroll
                for (int r=0; r<4; ++r)
                    #pragma unroll
                    for (int hs=0; hs<3; ++hs){
                        float vv = p[r][hs];
                        vv += __shfl_xor(vv, 16);
                        vv += __shfl_xor(vv, 32);
                        p[r][hs] = vv;
                    }
                // this lane keeps r == qq  (j = jl*4 + qq == jj)
                #pragma unroll
                for (int hs=0; hs<3; ++hs){
                    float vv = (qq==0) ? p[0][hs] : (qq==1) ? p[1][hs] : (qq==2) ? p[2][hs] : p[3][hs];
                    L[jt][hs] = vv;
                }
            } else {
                int jg = jt*64 + lane;
                const float4* kp  = (const float4*)(k  + (size_t)jg*192);
                const float4* gkp = (const float4*)(gk + (size_t)jg*144);
                #pragma unroll
                for (int hs=0; hs<3; ++hs){
                    int h = h0 + hs;
                    float sng = dot4f(qv4[h*4+0], kp[h*4+0]) + dot4f(qv4[h*4+1], kp[h*4+1])
                              + dot4f(qv4[h*4+2], kp[h*4+2]) + dot4f(qv4[h*4+3], kp[h*4+3]);
                    float fdot = dot4f(gq4[h*3+0], gkp[h*3+0]) + dot4f(gq4[h*3+1], gkp[h*3+1])
                               + dot4f(gq4[h*3+2], gkp[h*3+2]);
                    float d2 = qloc[336+h] + sqk[(size_t)jg*HD + h] - 2.0f*fdot;
                    L[jt][hs] = fmaf(SCALE_SINGLE, sng, qloc[348+h]*d2);
                }
            }
            __syncthreads();
        }
    }

    // exchange: single/frame waves deposit (lane=j); pair waves add at j=jj + softmax -> a_l
    float* S_l = zbase;
    if (wave >= 4){
        int base = (hg*64 + lane) * 37;
        #pragma unroll
        for (int jt=0; jt<12; ++jt)
            #pragma unroll
            for (int hs=0; hs<3; ++hs)
                S_l[base + jt*3 + hs] = L[jt][hs];
    }
    __syncthreads();
    if (wave < 4){
        int base = (hg*64 + jj) * 37;
        #pragma unroll
        for (int jt=0; jt<12; ++jt)
            #pragma unroll
            for (int hs=0; hs<3; ++hs)
                L[jt][hs] += S_l[base + jt*3 + hs];

        #pragma unroll
        for (int hs=0; hs<3; ++hs){
            float m = -1e30f;
            #pragma unroll
            for (int jt=0; jt<12; ++jt) m = fmaxf(m, L[jt][hs]);
            #pragma unroll
            for (int off=32; off; off>>=1) m = fmaxf(m, __shfl_xor(m, off));
            float ssum = 0.f;
            #pragma unroll
            for (int jt=0; jt<12; ++jt){ float e = __expf(L[jt][hs]-m); L[jt][hs]=e; ssum += e; }
            #pragma unroll
            for (int off=32; off; off>>=1) ssum += __shfl_xor(ssum, off);
            float inv = 1.0f/ssum;
            #pragma unroll
            for (int jt=0; jt<12; ++jt){
                a_l[h0+hs][jt*64 + jj] = L[jt][hs]*inv;
            }
        }
    }
    __syncthreads();   // a_l complete; exchange region free for phase B

    // ---------------- phase B (R12 verbatim) ----------------
    STAGEB(0, 0);

    int hs = 0;
    const float4* gsrc = nullptr;
    int gstride = 0;
    if (t < 384){ hs = t>>5; }
    else if (t < 432){ int u=t-384; hs = u>>2; gsrc = (const float4*)v  + hs*4 + (u&3); gstride = 48; }
    else if (t < 504){ int u=t-432; hs = u/6;  gsrc = (const float4*)gv + hs*6 + (u%6); gstride = 72; }
    float4 acc = {0.f,0.f,0.f,0.f};
    int c4 = t & 31;

    __syncthreads();   // STAGEB(0) drained

    for (int jt=0; jt<24; ++jt){
        int cur = jt & 1;
        if (jt+1 < 24) STAGEB(jt+1, cur^1);
        if (t < 384){
            const float4* arow4 = (const float4*)&a_l[hs][0];
            float4 af[8];
            #pragma unroll
            for (int m=0;m<8;m++) af[m] = arow4[jt*8 + m];
            const float4* zt4 = (const float4*)(zbase + (size_t)cur*4096);
            #pragma unroll
            for (int jj2=0;jj2<32;jj2++){
                float aw = ((const float*)af)[jj2];
                float4 zv = zt4[jj2*32 + c4];
                acc.x = fmaf(aw, zv.x, acc.x);
                acc.y = fmaf(aw, zv.y, acc.y);
                acc.z = fmaf(aw, zv.z, acc.z);
                acc.w = fmaf(aw, zv.w, acc.w);
            }
        } else if (t < 504){
            const float* arow = &a_l[hs][0];
            #pragma unroll
            for (int jj2=0;jj2<32;jj2++){
                int j = jt*32 + jj2;
                float aw = arow[j];
                float4 sv = gsrc[(size_t)j*gstride];
                acc.x = fmaf(aw, sv.x, acc.x);
                acc.y = fmaf(aw, sv.y, acc.y);
                acc.z = fmaf(aw, sv.z, acc.z);
                acc.w = fmaf(aw, sv.w, acc.w);
            }
        }
        __syncthreads();
    }

    if (t < 384){
        float4* dst = (float4*)(att + (size_t)i*DOUT + 192) + (hs*32 + c4);
        *dst = acc;
    } else if (t < 432){
        int u = t-384;
        float4* dst = (float4*)(att + (size_t)i*DOUT) + u;
        *dst = acc;
    } else if (t < 504){
        int u = t-432;
        ((float4*)so_l)[u] = acc;
    }
    __syncthreads();
    if (t < 96){
        int h = t >> 3, p = t & 7;
        float d0 = so_l[h*24+p*3+0] - tv[(size_t)i*3+0];
        float d1 = so_l[h*24+p*3+1] - tv[(size_t)i*3+1];
        float d2 = so_l[h*24+p*3+2] - tv[(size_t)i*3+2];
        const float* Ri = R + (size_t)i*9;
        float l0 = fmaf(Ri[0],d0, fmaf(Ri[3],d1, Ri[6]*d2));
        float l1 = fmaf(Ri[1],d0, fmaf(Ri[4],d1, Ri[7]*d2));
        float l2 = fmaf(Ri[2],d0, fmaf(Ri[5],d1, Ri[8]*d2));
        size_t base = (size_t)i*DOUT;
        att[base + 1728 + p*36 + h*3 + 0] = l0;
        att[base + 1728 + p*36 + h*3 + 1] = l1;
        att[base + 1728 + p*36 + h*3 + 2] = l2;
        att[base + 2016 + p*12 + h] = sqrtf(l0*l0 + l1*l1 + l2*l2);
    }
#undef STAGEL
#undef STAGEB
}

// ---------------- K4: final projection att @ Wout + bout ----------------
#define ROWS4 2
__global__ __launch_bounds__(384) void k_final(
    const float* __restrict__ att, const float* __restrict__ Wout, const float* __restrict__ bout,
    float* __restrict__ out)
{
    __shared__ float att_l[ROWS4*DOUT];
    int ib = blockIdx.x * ROWS4, t = threadIdx.x;
    for (int idx=t; idx<ROWS4*DOUT; idx+=384){
        att_l[idx] = att[(size_t)ib*DOUT + idx];
    }
    __syncthreads();
    float a0=0.f,a1=0.f,a2=0.f,a3=0.f;
    float b0=0.f,b1=0.f,b2=0.f,b3=0.f;
    #pragma unroll 4
    for (int d=0; d<DOUT; d+=4){
        float w0 = Wout[(size_t)(d+0)*CSD + t];
        float w1 = Wout[(size_t)(d+1)*CSD + t];
        float w2 = Wout[(size_t)(d+2)*CSD + t];
        float w3 = Wout[(size_t)(d+3)*CSD + t];
        a0 = fmaf(att_l[d+0], w0, a0);
        a1 = fmaf(att_l[d+1], w1, a1);
        a2 = fmaf(att_l[d+2], w2, a2);
        a3 = fmaf(att_l[d+3], w3, a3);
        b0 = fmaf(att_l[DOUT+d+0], w0, b0);
        b1 = fmaf(att_l[DOUT+d+1], w1, b1);
        b2 = fmaf(att_l[DOUT+d+2], w2, b2);
        b3 = fmaf(att_l[DOUT+d+3], w3, b3);
    }
    float bb = bout[t];
    out[(size_t)ib*CSD + t]     = bb + ((a0+a1)+(a2+a3));
    out[(size_t)(ib+1)*CSD + t] = bb + ((b0+b1)+(b2+b3));
}

extern "C" void kernel_launch(void* const* d_in, const int* in_sizes, int n_in,
                              void* d_out, int out_size, void* d_ws, size_t ws_size,
                              hipStream_t stream)
{
    const float* s   = (const float*)d_in[0];
    const float* z   = (const float*)d_in[1];
    const float* R   = (const float*)d_in[2];
    const float* tv  = (const float*)d_in[3];
    const float* Wq  = (const float*)d_in[4];
    const float* Wk  = (const float*)d_in[5];
    const float* Wv  = (const float*)d_in[6];
    const float* Wqp = (const float*)d_in[7];
    const float* Wkp = (const float*)d_in[8];
    const float* Wvp = (const float*)d_in[9];
    const float* Wb  = (const float*)d_in[10];
    const float* Wout= (const float*)d_in[11];
    const float* bout= (const float*)d_in[12];
    const float* sh  = (const float*)d_in[13];

    float* ws  = (float*)d_ws;
    float* q_  = ws;                 // 768*192
    float* k_  = q_  + 147456;       // 768*192
    float* v_  = k_  + 147456;       // 768*192
    float* gq_ = v_  + 147456;       // 768*144
    float* gk_ = gq_ + 110592;       // 768*144
    float* gv_ = gk_ + 110592;       // 768*288
    float* sqq_= gv_ + 221184;       // 768*12
    float* sqk_= sqq_ + 9216;        // 768*12
    float* att_= sqk_ + 9216;        // 768*2112
    float* out = (float*)d_out;

    hipLaunchKernelGGL(k_proj,  dim3(NN/II), dim3(384), 0, stream,
                       s,R,tv,Wq,Wk,Wv,Wqp,Wkp,Wvp, q_,k_,v_,gq_,gk_,gv_,sqq_,sqk_);
    hipLaunchKernelGGL(k_ipa,   dim3(NN),    dim3(512), 0, stream,
                       z,Wb,sh,q_,k_,gq_,gk_,sqq_,sqk_, v_,gv_,R,tv, att_);
    hipLaunchKernelGGL(k_final, dim3(NN/ROWS4), dim3(384), 0, stream,
                       att_,Wout,bout, out);
}

// Round 15
// 436.863 us; speedup vs baseline: 1.3483x; 1.0441x over previous
//
#include <hip/hip_runtime.h>
#include <hip/hip_bf16.h>

#define NN 768
#define CSD 384
#define CZD 128
#define HD 12
#define DOUT 2112
#define II 2

#define SCALE_SINGLE 0.25f
#define SCALE_FRAME (-0.11785113019775793f)   /* -1/sqrt(72) */

__device__ __forceinline__ float dot4f(float4 a, float4 b){
    return fmaf(a.x,b.x, fmaf(a.y,b.y, fmaf(a.z,b.z, a.w*b.w)));
}

// ---------------- K1: projections + frame apply, II=2 residues per block ----------------
__global__ __launch_bounds__(384) void k_proj(
    const float* __restrict__ s, const float* __restrict__ R, const float* __restrict__ tv,
    const float* __restrict__ Wq, const float* __restrict__ Wk, const float* __restrict__ Wv,
    const float* __restrict__ Wqp, const float* __restrict__ Wkp, const float* __restrict__ Wvp,
    float* __restrict__ q, float* __restrict__ k, float* __restrict__ v,
    float* __restrict__ gq, float* __restrict__ gk, float* __restrict__ gv,
    float* __restrict__ sqq, float* __restrict__ sqk)
{
    __shared__ float s_l[II*CSD];
    __shared__ float praw[II][576];
    __shared__ float sq_pt[II][96];
    int i0 = blockIdx.x * II, t = threadIdx.x;
    if (t < II*CSD/4){
        const float4* s4 = (const float4*)(s + (size_t)i0*CSD);
        ((float4*)s_l)[t] = s4[t];
    }
    __syncthreads();

    int cols[3] = {t, t+384, t+768};
    const float* Wp[3]; int st[3], lc[3];
    #pragma unroll
    for (int m=0;m<3;m++){
        int c = cols[m];
        if (c < 192){ Wp[m]=Wq;  st[m]=192; lc[m]=c; }
        else if (c < 384){ Wp[m]=Wk;  st[m]=192; lc[m]=c-192; }
        else if (c < 576){ Wp[m]=Wv;  st[m]=192; lc[m]=c-384; }
        else if (c < 720){ Wp[m]=Wqp; st[m]=144; lc[m]=c-576; }
        else if (c < 864){ Wp[m]=Wkp; st[m]=144; lc[m]=c-720; }
        else { Wp[m]=Wvp; st[m]=288; lc[m]=c-864; }
    }
    float acc[3][II];
    #pragma unroll
    for (int m=0;m<3;m++)
        #pragma unroll
        for (int ii=0;ii<II;ii++) acc[m][ii]=0.f;

    #pragma unroll 4
    for (int r=0;r<CSD;r++){
        float w0 = Wp[0][(size_t)r*st[0]+lc[0]];
        float w1 = Wp[1][(size_t)r*st[1]+lc[1]];
        float w2 = Wp[2][(size_t)r*st[2]+lc[2]];
        #pragma unroll
        for (int ii=0;ii<II;ii++){
            float sv = s_l[ii*CSD + r];
            acc[0][ii] = fmaf(sv, w0, acc[0][ii]);
            acc[1][ii] = fmaf(sv, w1, acc[1][ii]);
            acc[2][ii] = fmaf(sv, w2, acc[2][ii]);
        }
    }
    #pragma unroll
    for (int m=0;m<3;m++){
        int c = cols[m];
        #pragma unroll
        for (int ii=0;ii<II;ii++){
            float val = acc[m][ii];
            size_t i = i0 + ii;
            if (c < 192) q[i*192 + c] = val;
            else if (c < 384) k[i*192 + (c-192)] = val;
            else if (c < 576) v[i*192 + (c-384)] = val;
            else praw[ii][c-576] = val;
        }
    }
    __syncthreads();

    if (t < 192){
        #pragma unroll
        for (int ii=0;ii<II;ii++){
            size_t i = i0 + ii;
            const float* Ri = R + i*9;
            float R00=Ri[0],R01=Ri[1],R02=Ri[2];
            float R10=Ri[3],R11=Ri[4],R12=Ri[5];
            float R20=Ri[6],R21=Ri[7],R22=Ri[8];
            float t0=tv[i*3+0],t1=tv[i*3+1],t2=tv[i*3+2];
            int src; float* dst; int sqslot=-1;
            if (t < 48){ src = t*3; dst = gq + i*144 + t*3; sqslot = t; }
            else if (t < 96){ int u=t-48; src = 144+u*3; dst = gk + i*144 + u*3; sqslot = 48+u; }
            else { int u=t-96; src = 288+u*3; dst = gv + i*288 + u*3; }
            float x=praw[ii][src], y=praw[ii][src+1], zc=praw[ii][src+2];
            float g0 = fmaf(R00,x, fmaf(R01,y, fmaf(R02,zc, t0)));
            float g1 = fmaf(R10,x, fmaf(R11,y, fmaf(R12,zc, t1)));
            float g2 = fmaf(R20,x, fmaf(R21,y, fmaf(R22,zc, t2)));
            dst[0]=g0; dst[1]=g1; dst[2]=g2;
            if (sqslot >= 0) sq_pt[ii][sqslot] = g0*g0 + g1*g1 + g2*g2;
        }
    }
    __syncthreads();
    if (t < II*HD){
        int ii = t / HD, h = t % HD;
        float s1 = sq_pt[ii][h*4]+sq_pt[ii][h*4+1]+sq_pt[ii][h*4+2]+sq_pt[ii][h*4+3];
        float s2 = sq_pt[ii][48+h*4]+sq_pt[ii][48+h*4+1]+sq_pt[ii][48+h*4+2]+sq_pt[ii][48+h*4+3];
        sqq[(size_t)(i0+ii)*HD + h] = s1;
        sqk[(size_t)(i0+ii)*HD + h] = s2;
    }
}

// ---------------- K2: fused IPA (R12 phase A; phase B 64-row tiles, 2 heads/lane) ----------------
// block = one i, 512 threads = 8 waves, LDS ~109KB -> 1 block/CU.
// Phase A (R12 verbatim): 12x 64-row swizzled z tiles, syncthreads dbuf;
//   waves 0-3 pair (lane=row), waves 4-7 single+frame; exchange; softmax -> a_l.
// Phase B (new): 12x 64-row LINEAR tiles (reuses full 64KB ztile as 2x32KB dbuf).
//   Waves 0-5: o_z with lane=(c4=lane&31, jhalf=lane>>5), heads {2w, 2w+1}:
//   each z ds_read feeds 2 heads' FMAs and each lane covers only its j-half
//   -> z-read issue HALVED vs R12 (z element read 6x not 12x). Halves combined
//   with 8 shfl_xor(32) at the end; jhalf==0 lanes write. o_s/so threads as R12
//   but 64 j per tile. Bank pattern unchanged (stride-16B over contiguous 512B).
__global__ __launch_bounds__(512) void k_ipa(
    const float* __restrict__ z, const float* __restrict__ Wb, const float* __restrict__ scale_head,
    const float* __restrict__ q, const float* __restrict__ k,
    const float* __restrict__ gq, const float* __restrict__ gk,
    const float* __restrict__ sqq, const float* __restrict__ sqk,
    const float* __restrict__ v, const float* __restrict__ gv,
    const float* __restrict__ R, const float* __restrict__ tv,
    float* __restrict__ att)
{
    __shared__ float ztile[2][64][CZD];   // 64KB: phase-A dbuf; reused as exchange + phase-B dbuf
    __shared__ float wbT[HD*CZD];         // [h][c]
    __shared__ float qloc[360];           // q(192) gq(144) sqq(12) sp(12)
    __shared__ float a_l[HD][NN];         // softmax'd attention, block-local
    __shared__ float so_l[288];

    int i = blockIdx.x, t = threadIdx.x;
    int wave = t >> 6, lane = t & 63;

    for (int idx=t; idx<HD*CZD; idx+=512){
        int h = idx >> 7, c = idx & 127;
        wbT[idx] = Wb[(size_t)c*HD + h];
    }
    if (t < 192) qloc[t] = q[(size_t)i*192 + t];
    else if (t < 336) qloc[t] = gq[(size_t)i*144 + (t-192)];
    else if (t < 348) qloc[t] = sqq[(size_t)i*HD + (t-336)];
    else if (t < 360){
        int h = t-348;
        float shv = scale_head[h];
        float sp = (shv > 20.f) ? shv : log1pf(__expf(shv));
        qloc[t] = SCALE_FRAME * sp;
    }

    const char* zi = (const char*)(z + (size_t)i*NN*CZD);
    float* zbase = &ztile[0][0][0];

    // phase A: 64-row tile (32KB), linear LDS dest, inverse-swizzled global src; all 512 threads
#define STAGEL(JT, BUF) do { \
    const char* _zb = zi + (size_t)(JT)*32768; \
    char* _lb = (char*)zbase + (size_t)(BUF)*32768; \
    _Pragma("unroll") \
    for (int _m=0;_m<4;_m++){ \
        int _d = t*16 + _m*8192; \
        int _j = _d >> 9; \
        int _b = _d & 511; \
        int _sb = _b ^ ((_j & 31) << 4); \
        __builtin_amdgcn_global_load_lds((const __attribute__((address_space(1))) void*)(_zb + (size_t)_j*512 + _sb), \
            (__attribute__((address_space(3))) void*)(_lb + _d), 16, 0, 0); \
    } \
  } while(0)

    // phase B: 64-row tile (32KB), linear both sides; all 512 threads (4 x 16B each)
#define STAGEB(JT, BUF) do { \
    const char* _zb = zi + (size_t)(JT)*32768; \
    char* _lb = (char*)zbase + (size_t)(BUF)*32768; \
    _Pragma("unroll") \
    for (int _m=0;_m<4;_m++){ \
        int _d = t*16 + _m*8192; \
        __builtin_amdgcn_global_load_lds((const __attribute__((address_space(1))) void*)(_zb + _d), \
            (__attribute__((address_space(3))) void*)(_lb + _d), 16, 0, 0); \
    } \
  } while(0)

    STAGEL(0, 0);

    int hg = (wave < 4) ? wave : (wave - 4);
    int h0 = hg * 3;
    float L[12][3];

    __syncthreads();   // wbT/qloc visible; STAGEL(0) drained

    {
        const float4* wb4 = (const float4*)wbT;
        const float4* qv4 = (const float4*)qloc;
        const float4* gq4 = (const float4*)(qloc + 192);
        int xoff = (lane & 31) << 4;

        for (int jt=0; jt<12; ++jt){
            int cur = jt & 1;
            if (jt+1 < 12) STAGEL(jt+1, cur^1);
            if (wave < 4){
                const char* zb = (const char*)(zbase + (size_t)cur*8192) + lane*512;
                float p0=0.f, p1=0.f, p2=0.f;
                #pragma unroll 8
                for (int c4=0; c4<32; ++c4){
                    float4 zv = *(const float4*)(zb + ((c4*16) ^ xoff));
                    p0 += dot4f(zv, wb4[(h0+0)*32 + c4]);
                    p1 += dot4f(zv, wb4[(h0+1)*32 + c4]);
                    p2 += dot4f(zv, wb4[(h0+2)*32 + c4]);
                }
                L[jt][0]=p0; L[jt][1]=p1; L[jt][2]=p2;
            } else {
                int jg = jt*64 + lane;
                const float4* kp  = (const float4*)(k  + (size_t)jg*192);
                const float4* gkp = (const float4*)(gk + (size_t)jg*144);
                #pragma unroll
                for (int hs=0; hs<3; ++hs){
                    int h = h0 + hs;
                    float sng = dot4f(qv4[h*4+0], kp[h*4+0]) + dot4f(qv4[h*4+1], kp[h*4+1])
                              + dot4f(qv4[h*4+2], kp[h*4+2]) + dot4f(qv4[h*4+3], kp[h*4+3]);
                    float fdot = dot4f(gq4[h*3+0], gkp[h*3+0]) + dot4f(gq4[h*3+1], gkp[h*3+1])
                               + dot4f(gq4[h*3+2], gkp[h*3+2]);
                    float d2 = qloc[336+h] + sqk[(size_t)jg*HD + h] - 2.0f*fdot;
                    L[jt][hs] = fmaf(SCALE_SINGLE, sng, qloc[348+h]*d2);
                }
            }
            __syncthreads();
        }
    }

    // exchange: single/frame waves deposit; pair waves add + softmax -> a_l
    float* S_l = zbase;
    if (wave >= 4){
        int base = (hg*64 + lane) * 37;
        #pragma unroll
        for (int jt=0; jt<12; ++jt)
            #pragma unroll
            for (int hs=0; hs<3; ++hs)
                S_l[base + jt*3 + hs] = L[jt][hs];
    }
    __syncthreads();
    if (wave < 4){
        int base = (hg*64 + lane) * 37;
        #pragma unroll
        for (int jt=0; jt<12; ++jt)
            #pragma unroll
            for (int hs=0; hs<3; ++hs)
                L[jt][hs] += S_l[base + jt*3 + hs];

        #pragma unroll
        for (int hs=0; hs<3; ++hs){
            float m = -1e30f;
            #pragma unroll
            for (int jt=0; jt<12; ++jt) m = fmaxf(m, L[jt][hs]);
            #pragma unroll
            for (int off=32; off; off>>=1) m = fmaxf(m, __shfl_xor(m, off));
            float ssum = 0.f;
            #pragma unroll
            for (int jt=0; jt<12; ++jt){ float e = __expf(L[jt][hs]-m); L[jt][hs]=e; ssum += e; }
            #pragma unroll
            for (int off=32; off; off>>=1) ssum += __shfl_xor(ssum, off);
            float inv = 1.0f/ssum;
            #pragma unroll
            for (int jt=0; jt<12; ++jt){
                a_l[h0+hs][jt*64 + lane] = L[jt][hs]*inv;
            }
        }
    }
    __syncthreads();   // a_l complete; exchange region free for phase B

    // ---------------- phase B: 12 x 64-row linear tiles ----------------
    STAGEB(0, 0);

    int c4 = lane & 31, jhalf = lane >> 5;
    int h0b = wave*2;                      // waves 0-5: heads {2w, 2w+1}
    float4 azA = {0,0,0,0}, azB = {0,0,0,0};
    float4 accs = {0,0,0,0};
    const float4* gsrc = nullptr; int gstride = 0; int hso = 0;
    if (t >= 384 && t < 432){ int u=t-384; hso = u>>2; gsrc = (const float4*)v  + hso*4 + (u&3); gstride = 48; }
    else if (t >= 432 && t < 504){ int u=t-432; hso = u/6;  gsrc = (const float4*)gv + hso*6 + (u%6); gstride = 72; }

    __syncthreads();   // STAGEB(0) drained

    for (int jt=0; jt<12; ++jt){
        int cur = jt & 1;
        if (jt+1 < 12) STAGEB(jt+1, cur^1);
        if (t < 384){
            const float4* aA = (const float4*)&a_l[h0b  ][0] + jt*16 + jhalf*8;
            const float4* aB = (const float4*)&a_l[h0b+1][0] + jt*16 + jhalf*8;
            float4 afA[8], afB[8];
            #pragma unroll
            for (int m=0;m<8;m++){ afA[m]=aA[m]; afB[m]=aB[m]; }
            const float4* zt4 = (const float4*)(zbase + (size_t)cur*8192) + (size_t)jhalf*1024;
            #pragma unroll
            for (int jj=0;jj<32;jj++){
                float4 zv = zt4[jj*32 + c4];
                float wa = ((const float*)afA)[jj];
                float wb = ((const float*)afB)[jj];
                azA.x = fmaf(wa, zv.x, azA.x);
                azA.y = fmaf(wa, zv.y, azA.y);
                azA.z = fmaf(wa, zv.z, azA.z);
                azA.w = fmaf(wa, zv.w, azA.w);
                azB.x = fmaf(wb, zv.x, azB.x);
                azB.y = fmaf(wb, zv.y, azB.y);
                azB.z = fmaf(wb, zv.z, azB.z);
                azB.w = fmaf(wb, zv.w, azB.w);
            }
        } else if (t < 504){
            const float* arow = &a_l[hso][0];
            #pragma unroll
            for (int jj=0;jj<64;jj++){
                int j = jt*64 + jj;
                float aw = arow[j];
                float4 sv = gsrc[(size_t)j*gstride];
                accs.x = fmaf(aw, sv.x, accs.x);
                accs.y = fmaf(aw, sv.y, accs.y);
                accs.z = fmaf(aw, sv.z, accs.z);
                accs.w = fmaf(aw, sv.w, accs.w);
            }
        }
        __syncthreads();
    }

    // combine j-halves (waves 0-5), then write epilogue
    if (t < 384){
        azA.x += __shfl_xor(azA.x, 32); azA.y += __shfl_xor(azA.y, 32);
        azA.z += __shfl_xor(azA.z, 32); azA.w += __shfl_xor(azA.w, 32);
        azB.x += __shfl_xor(azB.x, 32); azB.y += __shfl_xor(azB.y, 32);
        azB.z += __shfl_xor(azB.z, 32); azB.w += __shfl_xor(azB.w, 32);
        if (jhalf == 0){
            *(float4*)(att + (size_t)i*DOUT + 192 + (h0b  )*128 + c4*4) = azA;
            *(float4*)(att + (size_t)i*DOUT + 192 + (h0b+1)*128 + c4*4) = azB;
        }
    } else if (t < 432){
        int u = t-384;
        ((float4*)(att + (size_t)i*DOUT))[u] = accs;
    } else if (t < 504){
        int u = t-432;
        ((float4*)so_l)[u] = accs;
    }
    __syncthreads();
    if (t < 96){
        int h = t >> 3, p = t & 7;
        float d0 = so_l[h*24+p*3+0] - tv[(size_t)i*3+0];
        float d1 = so_l[h*24+p*3+1] - tv[(size_t)i*3+1];
        float d2 = so_l[h*24+p*3+2] - tv[(size_t)i*3+2];
        const float* Ri = R + (size_t)i*9;
        float l0 = fmaf(Ri[0],d0, fmaf(Ri[3],d1, Ri[6]*d2));
        float l1 = fmaf(Ri[1],d0, fmaf(Ri[4],d1, Ri[7]*d2));
        float l2 = fmaf(Ri[2],d0, fmaf(Ri[5],d1, Ri[8]*d2));
        size_t base = (size_t)i*DOUT;
        att[base + 1728 + p*36 + h*3 + 0] = l0;
        att[base + 1728 + p*36 + h*3 + 1] = l1;
        att[base + 1728 + p*36 + h*3 + 2] = l2;
        att[base + 2016 + p*12 + h] = sqrtf(l0*l0 + l1*l1 + l2*l2);
    }
#undef STAGEL
#undef STAGEB
}

// ---------------- K4: final projection att @ Wout + bout ----------------
#define ROWS4 2
__global__ __launch_bounds__(384) void k_final(
    const float* __restrict__ att, const float* __restrict__ Wout, const float* __restrict__ bout,
    float* __restrict__ out)
{
    __shared__ float att_l[ROWS4*DOUT];
    int ib = blockIdx.x * ROWS4, t = threadIdx.x;
    for (int idx=t; idx<ROWS4*DOUT; idx+=384){
        att_l[idx] = att[(size_t)ib*DOUT + idx];
    }
    __syncthreads();
    float a0=0.f,a1=0.f,a2=0.f,a3=0.f;
    float b0=0.f,b1=0.f,b2=0.f,b3=0.f;
    #pragma unroll 4
    for (int d=0; d<DOUT; d+=4){
        float w0 = Wout[(size_t)(d+0)*CSD + t];
        float w1 = Wout[(size_t)(d+1)*CSD + t];
        float w2 = Wout[(size_t)(d+2)*CSD + t];
        float w3 = Wout[(size_t)(d+3)*CSD + t];
        a0 = fmaf(att_l[d+0], w0, a0);
        a1 = fmaf(att_l[d+1], w1, a1);
        a2 = fmaf(att_l[d+2], w2, a2);
        a3 = fmaf(att_l[d+3], w3, a3);
        b0 = fmaf(att_l[DOUT+d+0], w0, b0);
        b1 = fmaf(att_l[DOUT+d+1], w1, b1);
        b2 = fmaf(att_l[DOUT+d+2], w2, b2);
        b3 = fmaf(att_l[DOUT+d+3], w3, b3);
    }
    float bb = bout[t];
    out[(size_t)ib*CSD + t]     = bb + ((a0+a1)+(a2+a3));
    out[(size_t)(ib+1)*CSD + t] = bb + ((b0+b1)+(b2+b3));
}

extern "C" void kernel_launch(void* const* d_in, const int* in_sizes, int n_in,
                              void* d_out, int out_size, void* d_ws, size_t ws_size,
                              hipStream_t stream)
{
    const float* s   = (const float*)d_in[0];
    const float* z   = (const float*)d_in[1];
    const float* R   = (const float*)d_in[2];
    const float* tv  = (const float*)d_in[3];
    const float* Wq  = (const float*)d_in[4];
    const float* Wk  = (const float*)d_in[5];
    const float* Wv  = (const float*)d_in[6];
    const float* Wqp = (const float*)d_in[7];
    const float* Wkp = (const float*)d_in[8];
    const float* Wvp = (const float*)d_in[9];
    const float* Wb  = (const float*)d_in[10];
    const float* Wout= (const float*)d_in[11];
    const float* bout= (const float*)d_in[12];
    const float* sh  = (const float*)d_in[13];

    float* ws  = (float*)d_ws;
    float* q_  = ws;                 // 768*192
    float* k_  = q_  + 147456;       // 768*192
    float* v_  = k_  + 147456;       // 768*192
    float* gq_ = v_  + 147456;       // 768*144
    float* gk_ = gq_ + 110592;       // 768*144
    float* gv_ = gk_ + 110592;       // 768*288
    float* sqq_= gv_ + 221184;       // 768*12
    float* sqk_= sqq_ + 9216;        // 768*12
    float* att_= sqk_ + 9216;        // 768*2112
    float* out = (float*)d_out;

    hipLaunchKernelGGL(k_proj,  dim3(NN/II), dim3(384), 0, stream,
                       s,R,tv,Wq,Wk,Wv,Wqp,Wkp,Wvp, q_,k_,v_,gq_,gk_,gv_,sqq_,sqk_);
    hipLaunchKernelGGL(k_ipa,   dim3(NN),    dim3(512), 0, stream,
                       z,Wb,sh,q_,k_,gq_,gk_,sqq_,sqk_, v_,gv_,R,tv, att_);
    hipLaunchKernelGGL(k_final, dim3(NN/ROWS4), dim3(384), 0, stream,
                       att_,Wout,bout, out);
}

// Round 16
// 390.988 us; speedup vs baseline: 1.5065x; 1.1173x over previous
//
#include <hip/hip_runtime.h>
#include <hip/hip_bf16.h>

#define NN 768
#define CSD 384
#define CZD 128
#define HD 12
#define DOUT 2112
#define II 2

#define SCALE_SINGLE 0.25f
#define SCALE_FRAME (-0.11785113019775793f)   /* -1/sqrt(72) */

// bf16 weight pool offsets (ushort elems)
#define OFF_WQ   0
#define OFF_WK   73728
#define OFF_WV   147456
#define OFF_WQP  221184
#define OFF_WKP  276480
#define OFF_WVP  331776
#define OFF_WOUT 442368
#define NBF_TOTAL 1253376   /* 442368 + 811008 */

__device__ __forceinline__ float dot4f(float4 a, float4 b){
    return fmaf(a.x,b.x, fmaf(a.y,b.y, fmaf(a.z,b.z, a.w*b.w)));
}
__device__ __forceinline__ unsigned short f2bf(float f){   // fp32 -> bf16 (RNE)
    unsigned u = __float_as_uint(f);
    return (unsigned short)((u + 0x7fffu + ((u >> 16) & 1u)) >> 16);
}
__device__ __forceinline__ float bf2f(unsigned short u){
    return __uint_as_float(((unsigned)u) << 16);
}

// ---------------- K0: one-shot weight conversion fp32 -> bf16 into ws ----------------
__global__ __launch_bounds__(256) void k_conv(
    const float* __restrict__ Wq, const float* __restrict__ Wk, const float* __restrict__ Wv,
    const float* __restrict__ Wqp, const float* __restrict__ Wkp, const float* __restrict__ Wvp,
    const float* __restrict__ Wout, unsigned short* __restrict__ dst)
{
    int idx = blockIdx.x*256 + threadIdx.x;
    if (idx >= NBF_TOTAL) return;
    const float* src; int off = idx;
    if (idx < OFF_WK)        { src = Wq;  }
    else if (idx < OFF_WV)   { src = Wk;  off -= OFF_WK;  }
    else if (idx < OFF_WQP)  { src = Wv;  off -= OFF_WV;  }
    else if (idx < OFF_WKP)  { src = Wqp; off -= OFF_WQP; }
    else if (idx < OFF_WVP)  { src = Wkp; off -= OFF_WKP; }
    else if (idx < OFF_WOUT) { src = Wvp; off -= OFF_WVP; }
    else                     { src = Wout; off -= OFF_WOUT; }
    dst[idx] = f2bf(src[off]);
}

// ---------------- K1: projections + frame apply, II=2, bf16 weight stream ----------------
__global__ __launch_bounds__(384) void k_proj(
    const float* __restrict__ s, const float* __restrict__ R, const float* __restrict__ tv,
    const unsigned short* __restrict__ wbf,
    float* __restrict__ q, float* __restrict__ k, float* __restrict__ v,
    float* __restrict__ gq, float* __restrict__ gk, float* __restrict__ gv,
    float* __restrict__ sqq, float* __restrict__ sqk)
{
    __shared__ float s_l[II*CSD];
    __shared__ float praw[II][576];
    __shared__ float sq_pt[II][96];
    int i0 = blockIdx.x * II, t = threadIdx.x;
    if (t < II*CSD/4){
        const float4* s4 = (const float4*)(s + (size_t)i0*CSD);
        ((float4*)s_l)[t] = s4[t];
    }
    __syncthreads();

    int cols[3] = {t, t+384, t+768};
    const unsigned short* Wp[3]; int st[3], lc[3];
    #pragma unroll
    for (int m=0;m<3;m++){
        int c = cols[m];
        if (c < 192){ Wp[m]=wbf+OFF_WQ;  st[m]=192; lc[m]=c; }
        else if (c < 384){ Wp[m]=wbf+OFF_WK;  st[m]=192; lc[m]=c-192; }
        else if (c < 576){ Wp[m]=wbf+OFF_WV;  st[m]=192; lc[m]=c-384; }
        else if (c < 720){ Wp[m]=wbf+OFF_WQP; st[m]=144; lc[m]=c-576; }
        else if (c < 864){ Wp[m]=wbf+OFF_WKP; st[m]=144; lc[m]=c-720; }
        else { Wp[m]=wbf+OFF_WVP; st[m]=288; lc[m]=c-864; }
    }
    float acc[3][II];
    #pragma unroll
    for (int m=0;m<3;m++)
        #pragma unroll
        for (int ii=0;ii<II;ii++) acc[m][ii]=0.f;

    #pragma unroll 4
    for (int r=0;r<CSD;r++){
        float w0 = bf2f(Wp[0][(size_t)r*st[0]+lc[0]]);
        float w1 = bf2f(Wp[1][(size_t)r*st[1]+lc[1]]);
        float w2 = bf2f(Wp[2][(size_t)r*st[2]+lc[2]]);
        #pragma unroll
        for (int ii=0;ii<II;ii++){
            float sv = s_l[ii*CSD + r];
            acc[0][ii] = fmaf(sv, w0, acc[0][ii]);
            acc[1][ii] = fmaf(sv, w1, acc[1][ii]);
            acc[2][ii] = fmaf(sv, w2, acc[2][ii]);
        }
    }
    #pragma unroll
    for (int m=0;m<3;m++){
        int c = cols[m];
        #pragma unroll
        for (int ii=0;ii<II;ii++){
            float val = acc[m][ii];
            size_t i = i0 + ii;
            if (c < 192) q[i*192 + c] = val;
            else if (c < 384) k[i*192 + (c-192)] = val;
            else if (c < 576) v[i*192 + (c-384)] = val;
            else praw[ii][c-576] = val;
        }
    }
    __syncthreads();

    if (t < 192){
        #pragma unroll
        for (int ii=0;ii<II;ii++){
            size_t i = i0 + ii;
            const float* Ri = R + i*9;
            float R00=Ri[0],R01=Ri[1],R02=Ri[2];
            float R10=Ri[3],R11=Ri[4],R12=Ri[5];
            float R20=Ri[6],R21=Ri[7],R22=Ri[8];
            float t0=tv[i*3+0],t1=tv[i*3+1],t2=tv[i*3+2];
            int src; float* dst; int sqslot=-1;
            if (t < 48){ src = t*3; dst = gq + i*144 + t*3; sqslot = t; }
            else if (t < 96){ int u=t-48; src = 144+u*3; dst = gk + i*144 + u*3; sqslot = 48+u; }
            else { int u=t-96; src = 288+u*3; dst = gv + i*288 + u*3; }
            float x=praw[ii][src], y=praw[ii][src+1], zc=praw[ii][src+2];
            float g0 = fmaf(R00,x, fmaf(R01,y, fmaf(R02,zc, t0)));
            float g1 = fmaf(R10,x, fmaf(R11,y, fmaf(R12,zc, t1)));
            float g2 = fmaf(R20,x, fmaf(R21,y, fmaf(R22,zc, t2)));
            dst[0]=g0; dst[1]=g1; dst[2]=g2;
            if (sqslot >= 0) sq_pt[ii][sqslot] = g0*g0 + g1*g1 + g2*g2;
        }
    }
    __syncthreads();
    if (t < II*HD){
        int ii = t / HD, h = t % HD;
        float s1 = sq_pt[ii][h*4]+sq_pt[ii][h*4+1]+sq_pt[ii][h*4+2]+sq_pt[ii][h*4+3];
        float s2 = sq_pt[ii][48+h*4]+sq_pt[ii][48+h*4+1]+sq_pt[ii][48+h*4+2]+sq_pt[ii][48+h*4+3];
        sqq[(size_t)(i0+ii)*HD + h] = s1;
        sqk[(size_t)(i0+ii)*HD + h] = s2;
    }
}

// ---------------- K2: fused IPA (R12 verbatim — measured best 313 us) ----------------
__global__ __launch_bounds__(512) void k_ipa(
    const float* __restrict__ z, const float* __restrict__ Wb, const float* __restrict__ scale_head,
    const float* __restrict__ q, const float* __restrict__ k,
    const float* __restrict__ gq, const float* __restrict__ gk,
    const float* __restrict__ sqq, const float* __restrict__ sqk,
    const float* __restrict__ v, const float* __restrict__ gv,
    const float* __restrict__ R, const float* __restrict__ tv,
    float* __restrict__ att)
{
    __shared__ float ztile[2][64][CZD];   // 64KB: phase-A dbuf; reused as exchange + phase-B dbuf
    __shared__ float wbT[HD*CZD];         // [h][c]
    __shared__ float qloc[360];           // q(192) gq(144) sqq(12) sp(12)
    __shared__ float a_l[HD][NN];         // softmax'd attention, block-local
    __shared__ float so_l[288];

    int i = blockIdx.x, t = threadIdx.x;
    int wave = t >> 6, lane = t & 63;

    for (int idx=t; idx<HD*CZD; idx+=512){
        int h = idx >> 7, c = idx & 127;
        wbT[idx] = Wb[(size_t)c*HD + h];
    }
    if (t < 192) qloc[t] = q[(size_t)i*192 + t];
    else if (t < 336) qloc[t] = gq[(size_t)i*144 + (t-192)];
    else if (t < 348) qloc[t] = sqq[(size_t)i*HD + (t-336)];
    else if (t < 360){
        int h = t-348;
        float shv = scale_head[h];
        float sp = (shv > 20.f) ? shv : log1pf(__expf(shv));
        qloc[t] = SCALE_FRAME * sp;
    }

    const char* zi = (const char*)(z + (size_t)i*NN*CZD);
    float* zbase = &ztile[0][0][0];

#define STAGEL(JT, BUF) do { \
    const char* _zb = zi + (size_t)(JT)*32768; \
    char* _lb = (char*)zbase + (size_t)(BUF)*32768; \
    _Pragma("unroll") \
    for (int _m=0;_m<4;_m++){ \
        int _d = t*16 + _m*8192; \
        int _j = _d >> 9; \
        int _b = _d & 511; \
        int _sb = _b ^ ((_j & 31) << 4); \
        __builtin_amdgcn_global_load_lds((const __attribute__((address_space(1))) void*)(_zb + (size_t)_j*512 + _sb), \
            (__attribute__((address_space(3))) void*)(_lb + _d), 16, 0, 0); \
    } \
  } while(0)

#define STAGEB(JT, BUF) do { \
    const float* _s = (const float*)zi + (size_t)(JT)*4096 + t*4; \
    float* _d = zbase + (size_t)(BUF)*4096 + t*4; \
    __builtin_amdgcn_global_load_lds((const __attribute__((address_space(1))) void*)_s, \
        (__attribute__((address_space(3))) void*)_d, 16, 0, 0); \
    __builtin_amdgcn_global_load_lds((const __attribute__((address_space(1))) void*)(_s+2048), \
        (__attribute__((address_space(3))) void*)(_d+2048), 16, 0, 0); \
  } while(0)

    STAGEL(0, 0);

    int hg = (wave < 4) ? wave : (wave - 4);
    int h0 = hg * 3;
    float L[12][3];

    __syncthreads();   // wbT/qloc visible; STAGEL(0) drained

    {
        const float4* wb4 = (const float4*)wbT;
        const float4* qv4 = (const float4*)qloc;
        const float4* gq4 = (const float4*)(qloc + 192);
        int xoff = (lane & 31) << 4;

        for (int jt=0; jt<12; ++jt){
            int cur = jt & 1;
            if (jt+1 < 12) STAGEL(jt+1, cur^1);
            if (wave < 4){
                const char* zb = (const char*)(zbase + (size_t)cur*8192) + lane*512;
                float p0=0.f, p1=0.f, p2=0.f;
                #pragma unroll 8
                for (int c4=0; c4<32; ++c4){
                    float4 zv = *(const float4*)(zb + ((c4*16) ^ xoff));
                    p0 += dot4f(zv, wb4[(h0+0)*32 + c4]);
                    p1 += dot4f(zv, wb4[(h0+1)*32 + c4]);
                    p2 += dot4f(zv, wb4[(h0+2)*32 + c4]);
                }
                L[jt][0]=p0; L[jt][1]=p1; L[jt][2]=p2;
            } else {
                int jg = jt*64 + lane;
                const float4* kp  = (const float4*)(k  + (size_t)jg*192);
                const float4* gkp = (const float4*)(gk + (size_t)jg*144);
                #pragma unroll
                for (int hs=0; hs<3; ++hs){
                    int h = h0 + hs;
                    float sng = dot4f(qv4[h*4+0], kp[h*4+0]) + dot4f(qv4[h*4+1], kp[h*4+1])
                              + dot4f(qv4[h*4+2], kp[h*4+2]) + dot4f(qv4[h*4+3], kp[h*4+3]);
                    float fdot = dot4f(gq4[h*3+0], gkp[h*3+0]) + dot4f(gq4[h*3+1], gkp[h*3+1])
                               + dot4f(gq4[h*3+2], gkp[h*3+2]);
                    float d2 = qloc[336+h] + sqk[(size_t)jg*HD + h] - 2.0f*fdot;
                    L[jt][hs] = fmaf(SCALE_SINGLE, sng, qloc[348+h]*d2);
                }
            }
            __syncthreads();
        }
    }

    float* S_l = zbase;
    if (wave >= 4){
        int base = (hg*64 + lane) * 37;
        #pragma unroll
        for (int jt=0; jt<12; ++jt)
            #pragma unroll
            for (int hs=0; hs<3; ++hs)
                S_l[base + jt*3 + hs] = L[jt][hs];
    }
    __syncthreads();
    if (wave < 4){
        int base = (hg*64 + lane) * 37;
        #pragma unroll
        for (int jt=0; jt<12; ++jt)
            #pragma unroll
            for (int hs=0; hs<3; ++hs)
                L[jt][hs] += S_l[base + jt*3 + hs];

        #pragma unroll
        for (int hs=0; hs<3; ++hs){
            float m = -1e30f;
            #pragma unroll
            for (int jt=0; jt<12; ++jt) m = fmaxf(m, L[jt][hs]);
            #pragma unroll
            for (int off=32; off; off>>=1) m = fmaxf(m, __shfl_xor(m, off));
            float ssum = 0.f;
            #pragma unroll
            for (int jt=0; jt<12; ++jt){ float e = __expf(L[jt][hs]-m); L[jt][hs]=e; ssum += e; }
            #pragma unroll
            for (int off=32; off; off>>=1) ssum += __shfl_xor(ssum, off);
            float inv = 1.0f/ssum;
            #pragma unroll
            for (int jt=0; jt<12; ++jt){
                a_l[h0+hs][jt*64 + lane] = L[jt][hs]*inv;
            }
        }
    }
    __syncthreads();   // a_l complete; exchange region free for phase B

    STAGEB(0, 0);

    int hs = 0;
    const float4* gsrc = nullptr;
    int gstride = 0;
    if (t < 384){ hs = t>>5; }
    else if (t < 432){ int u=t-384; hs = u>>2; gsrc = (const float4*)v  + hs*4 + (u&3); gstride = 48; }
    else if (t < 504){ int u=t-432; hs = u/6;  gsrc = (const float4*)gv + hs*6 + (u%6); gstride = 72; }
    float4 acc = {0.f,0.f,0.f,0.f};
    int c4 = t & 31;

    __syncthreads();   // STAGEB(0) drained

    for (int jt=0; jt<24; ++jt){
        int cur = jt & 1;
        if (jt+1 < 24) STAGEB(jt+1, cur^1);
        if (t < 384){
            const float4* arow4 = (const float4*)&a_l[hs][0];
            float4 af[8];
            #pragma unroll
            for (int m=0;m<8;m++) af[m] = arow4[jt*8 + m];
            const float4* zt4 = (const float4*)(zbase + (size_t)cur*4096);
            #pragma unroll
            for (int jj=0;jj<32;jj++){
                float aw = ((const float*)af)[jj];
                float4 zv = zt4[jj*32 + c4];
                acc.x = fmaf(aw, zv.x, acc.x);
                acc.y = fmaf(aw, zv.y, acc.y);
                acc.z = fmaf(aw, zv.z, acc.z);
                acc.w = fmaf(aw, zv.w, acc.w);
            }
        } else if (t < 504){
            const float* arow = &a_l[hs][0];
            #pragma unroll
            for (int jj=0;jj<32;jj++){
                int j = jt*32 + jj;
                float aw = arow[j];
                float4 sv = gsrc[(size_t)j*gstride];
                acc.x = fmaf(aw, sv.x, acc.x);
                acc.y = fmaf(aw, sv.y, acc.y);
                acc.z = fmaf(aw, sv.z, acc.z);
                acc.w = fmaf(aw, sv.w, acc.w);
            }
        }
        __syncthreads();
    }

    if (t < 384){
        float4* dst = (float4*)(att + (size_t)i*DOUT + 192) + (hs*32 + c4);
        *dst = acc;
    } else if (t < 432){
        int u = t-384;
        float4* dst = (float4*)(att + (size_t)i*DOUT) + u;
        *dst = acc;
    } else if (t < 504){
        int u = t-432;
        ((float4*)so_l)[u] = acc;
    }
    __syncthreads();
    if (t < 96){
        int h = t >> 3, p = t & 7;
        float d0 = so_l[h*24+p*3+0] - tv[(size_t)i*3+0];
        float d1 = so_l[h*24+p*3+1] - tv[(size_t)i*3+1];
        float d2 = so_l[h*24+p*3+2] - tv[(size_t)i*3+2];
        const float* Ri = R + (size_t)i*9;
        float l0 = fmaf(Ri[0],d0, fmaf(Ri[3],d1, Ri[6]*d2));
        float l1 = fmaf(Ri[1],d0, fmaf(Ri[4],d1, Ri[7]*d2));
        float l2 = fmaf(Ri[2],d0, fmaf(Ri[5],d1, Ri[8]*d2));
        size_t base = (size_t)i*DOUT;
        att[base + 1728 + p*36 + h*3 + 0] = l0;
        att[base + 1728 + p*36 + h*3 + 1] = l1;
        att[base + 1728 + p*36 + h*3 + 2] = l2;
        att[base + 2016 + p*12 + h] = sqrtf(l0*l0 + l1*l1 + l2*l2);
    }
#undef STAGEL
#undef STAGEB
}

// ---------------- K4: final projection att @ Wout(bf16) + bout ----------------
#define ROWS4 2
__global__ __launch_bounds__(384) void k_final(
    const float* __restrict__ att, const unsigned short* __restrict__ wobf,
    const float* __restrict__ bout, float* __restrict__ out)
{
    __shared__ float att_l[ROWS4*DOUT];
    int ib = blockIdx.x * ROWS4, t = threadIdx.x;
    for (int idx=t; idx<ROWS4*DOUT; idx+=384){
        att_l[idx] = att[(size_t)ib*DOUT + idx];
    }
    __syncthreads();
    float a0=0.f,a1=0.f,a2=0.f,a3=0.f;
    float b0=0.f,b1=0.f,b2=0.f,b3=0.f;
    #pragma unroll 4
    for (int d=0; d<DOUT; d+=4){
        float w0 = bf2f(wobf[(size_t)(d+0)*CSD + t]);
        float w1 = bf2f(wobf[(size_t)(d+1)*CSD + t]);
        float w2 = bf2f(wobf[(size_t)(d+2)*CSD + t]);
        float w3 = bf2f(wobf[(size_t)(d+3)*CSD + t]);
        a0 = fmaf(att_l[d+0], w0, a0);
        a1 = fmaf(att_l[d+1], w1, a1);
        a2 = fmaf(att_l[d+2], w2, a2);
        a3 = fmaf(att_l[d+3], w3, a3);
        b0 = fmaf(att_l[DOUT+d+0], w0, b0);
        b1 = fmaf(att_l[DOUT+d+1], w1, b1);
        b2 = fmaf(att_l[DOUT+d+2], w2, b2);
        b3 = fmaf(att_l[DOUT+d+3], w3, b3);
    }
    float bb = bout[t];
    out[(size_t)ib*CSD + t]     = bb + ((a0+a1)+(a2+a3));
    out[(size_t)(ib+1)*CSD + t] = bb + ((b0+b1)+(b2+b3));
}

extern "C" void kernel_launch(void* const* d_in, const int* in_sizes, int n_in,
                              void* d_out, int out_size, void* d_ws, size_t ws_size,
                              hipStream_t stream)
{
    const float* s   = (const float*)d_in[0];
    const float* z   = (const float*)d_in[1];
    const float* R   = (const float*)d_in[2];
    const float* tv  = (const float*)d_in[3];
    const float* Wq  = (const float*)d_in[4];
    const float* Wk  = (const float*)d_in[5];
    const float* Wv  = (const float*)d_in[6];
    const float* Wqp = (const float*)d_in[7];
    const float* Wkp = (const float*)d_in[8];
    const float* Wvp = (const float*)d_in[9];
    const float* Wb  = (const float*)d_in[10];
    const float* Wout= (const float*)d_in[11];
    const float* bout= (const float*)d_in[12];
    const float* sh  = (const float*)d_in[13];

    float* ws  = (float*)d_ws;
    float* q_  = ws;                 // 768*192
    float* k_  = q_  + 147456;       // 768*192
    float* v_  = k_  + 147456;       // 768*192
    float* gq_ = v_  + 147456;       // 768*144
    float* gk_ = gq_ + 110592;       // 768*144
    float* gv_ = gk_ + 110592;       // 768*288
    float* sqq_= gv_ + 221184;       // 768*12
    float* sqk_= sqq_ + 9216;        // 768*12
    float* att_= sqk_ + 9216;        // 768*2112
    unsigned short* wbf = (unsigned short*)(att_ + 1622016);  // 1253376 ushorts
    float* out = (float*)d_out;

    hipLaunchKernelGGL(k_conv,  dim3((NBF_TOTAL+255)/256), dim3(256), 0, stream,
                       Wq,Wk,Wv,Wqp,Wkp,Wvp,Wout, wbf);
    hipLaunchKernelGGL(k_proj,  dim3(NN/II), dim3(384), 0, stream,
                       s,R,tv, wbf, q_,k_,v_,gq_,gk_,gv_,sqq_,sqk_);
    hipLaunchKernelGGL(k_ipa,   dim3(NN),    dim3(512), 0, stream,
                       z,Wb,sh,q_,k_,gq_,gk_,sqq_,sqk_, v_,gv_,R,tv, att_);
    hipLaunchKernelGGL(k_final, dim3(NN/ROWS4), dim3(384), 0, stream,
                       att_, wbf + OFF_WOUT, bout, out);
}